// Round 7
// baseline (104.992 us; speedup 1.0000x reference)
//
#include <hip/hip_runtime.h>
#include <hip/hip_bf16.h>

#define EPS 1e-8f

typedef __attribute__((ext_vector_type(8))) short short8;
typedef __attribute__((ext_vector_type(4))) float f32x4;

__device__ __forceinline__ unsigned short f2bf(float f) {
  union { float f; unsigned u; } v; v.f = f;
  unsigned r = v.u + 0x7fffu + ((v.u >> 16) & 1u);
  return (unsigned short)(r >> 16);
}
__device__ __forceinline__ float bf2f(unsigned short b) {
  union { unsigned u; float f; } v; v.u = ((unsigned)b) << 16;
  return v.f;
}
__device__ __forceinline__ unsigned pack_bf2(float lo, float hi) {
  unsigned r;
  asm("v_cvt_pk_bf16_f32 %0, %1, %2" : "=v"(r) : "v"(lo), "v"(hi));
  return r;
}

// ---------------- k0: build bf16 transposed weights --------------------------
__global__ __launch_bounds__(256) void k0_prep(const float* __restrict__ We1,
                                               const float* __restrict__ We2,
                                               const float* __restrict__ Wg1,
                                               const float* __restrict__ Wg2,
                                               const float* __restrict__ Wf,
                                               unsigned short* __restrict__ We1T,
                                               unsigned short* __restrict__ We2T,
                                               unsigned short* __restrict__ Wg1T,
                                               unsigned short* __restrict__ Wg2T,
                                               unsigned short* __restrict__ WfT) {
  int idx = blockIdx.x * 256 + threadIdx.x;     // 655360 total
  if (idx < 262144) {
    int n = idx >> 10, k = idx & 1023;
    We1T[idx] = f2bf(We1[k * 256 + n]);
  } else if (idx < 294912) {
    int e = idx - 262144;
    int n = e >> 8, k = e & 255;
    We2T[e] = f2bf(We2[k * 128 + n]);
  } else if (idx < 458752) {
    int e = idx - 294912;
    int n = e / 160, c = e % 160;
    float v = 0.f;
    if (c < 129) v = (n < 512) ? Wg1[c * 512 + n] : Wg1[(129 + c) * 512 + (n - 512)];
    Wg1T[e] = f2bf(v);
  } else if (idx < 589824) {
    int e = idx - 458752;
    int n = e >> 9, k = e & 511;
    Wg2T[e] = f2bf(Wg2[k * 256 + n]);
  } else {
    int e = idx - 589824;
    int n = e >> 8, k = e & 255;
    WfT[e] = f2bf(Wf[k * 256 + n]);
  }
}

// ---------------- k1: h_bf = bf16(relu(x @ We1 + be1)) -----------------------
__global__ __launch_bounds__(512, 2) void k1(const float* __restrict__ x,
                                             const unsigned short* __restrict__ We1T,
                                             const float* __restrict__ be1,
                                             unsigned short* __restrict__ h_bf) {
  __shared__ unsigned char As[2][8192];   // [16][256] bf16, swizzled
  int tid = threadIdx.x, lane = tid & 63, w = tid >> 6;
  int m0 = blockIdx.x * 16;
  int srow = tid >> 5, skk = (tid & 31) * 8;
  int cb = w * 32;
  int row = lane & 15, kg = (lane >> 4) * 8;

  f32x4 acc[2] = {{0,0,0,0},{0,0,0,0}};

  auto stage = [&](int kc, int buf) {
    const float* src = x + (size_t)(m0 + srow) * 1024 + kc * 256 + skk;
    float4 a = *reinterpret_cast<const float4*>(src);
    float4 b = *reinterpret_cast<const float4*>(src + 4);
    uint4 pv;
    pv.x = pack_bf2(a.x, a.y); pv.y = pack_bf2(a.z, a.w);
    pv.z = pack_bf2(b.x, b.y); pv.w = pack_bf2(b.z, b.w);
    int addr = (srow * 512 + skk * 2) ^ ((srow & 7) << 4);
    *reinterpret_cast<uint4*>(&As[buf][addr]) = pv;
  };

  stage(0, 0);
  __syncthreads();
  for (int kc = 0; kc < 4; ++kc) {
    if (kc < 3) stage(kc + 1, (kc + 1) & 1);
    short8 breg[2][8];
#pragma unroll
    for (int cf = 0; cf < 2; ++cf)
#pragma unroll
      for (int ks = 0; ks < 8; ++ks)
        breg[cf][ks] = *reinterpret_cast<const short8*>(
            We1T + (size_t)(cb + cf * 16 + row) * 1024 + kc * 256 + ks * 32 + kg);
    const unsigned char* hc = &As[kc & 1][0];
#pragma unroll
    for (int ks = 0; ks < 8; ++ks) {
      int aoff = (row * 512 + ks * 64 + kg * 2) ^ ((row & 7) << 4);
      short8 af = *reinterpret_cast<const short8*>(hc + aoff);
      acc[0] = __builtin_amdgcn_mfma_f32_16x16x32_bf16(af, breg[0][ks], acc[0], 0, 0, 0);
      acc[1] = __builtin_amdgcn_mfma_f32_16x16x32_bf16(af, breg[1][ks], acc[1], 0, 0, 0);
    }
    __syncthreads();
  }
#pragma unroll
  for (int cf = 0; cf < 2; ++cf) {
    int col = cb + cf * 16 + row;
    float bias = be1[col];
#pragma unroll
    for (int r = 0; r < 4; ++r) {
      int orow = m0 + (lane >> 4) * 4 + r;
      h_bf[(size_t)orow * 256 + col] = f2bf(fmaxf(acc[cf][r] + bias, 0.f));
    }
  }
}

// ---------------- k2: fused z=h@We2+be2 -> LN(T) -> zc(LDS) -> g_all quarter -
__global__ __launch_bounds__(256) void k2(const unsigned short* __restrict__ h_bf,
                                          const unsigned short* __restrict__ We2T,
                                          const float* __restrict__ be2,
                                          const float* __restrict__ gamma,
                                          const float* __restrict__ beta,
                                          const unsigned short* __restrict__ Wg1T,
                                          const float* __restrict__ bg1,
                                          unsigned short* __restrict__ g_all) {
  __shared__ unsigned char zcs[16384];   // [32][256] bf16 swizzled: h tile, then zc
  __shared__ float zb[32][132];
  int b = blockIdx.x >> 2, nq = blockIdx.x & 3;
  int tid = threadIdx.x, lane = tid & 63, w = tid >> 6;
  int row = lane & 15, kg = (lane >> 4) * 8;

  {
    int srow = tid >> 3, skk = (tid & 7) * 32;
#pragma unroll
    for (int q = 0; q < 4; ++q) {
      short8 v = *reinterpret_cast<const short8*>(
          h_bf + (size_t)(b * 32 + srow) * 256 + skk + q * 8);
      int addr = (srow * 512 + (skk + q * 8) * 2) ^ ((srow & 7) << 4);
      *reinterpret_cast<short8*>(&zcs[addr]) = v;
    }
  }
  short8 breg1[2][8];
#pragma unroll
  for (int cf = 0; cf < 2; ++cf)
#pragma unroll
    for (int ks = 0; ks < 8; ++ks)
      breg1[cf][ks] = *reinterpret_cast<const short8*>(
          We2T + (size_t)(w * 32 + cf * 16 + row) * 256 + ks * 32 + kg);
  __syncthreads();

  {
    f32x4 acc[2][2] = {{{0,0,0,0},{0,0,0,0}},{{0,0,0,0},{0,0,0,0}}};
#pragma unroll
    for (int ks = 0; ks < 8; ++ks) {
      int a0off = (row * 512 + ks * 64 + kg * 2) ^ ((row & 7) << 4);
      int a1off = ((16 + row) * 512 + ks * 64 + kg * 2) ^ ((row & 7) << 4);
      short8 a0 = *reinterpret_cast<const short8*>(&zcs[a0off]);
      short8 a1 = *reinterpret_cast<const short8*>(&zcs[a1off]);
#pragma unroll
      for (int cf = 0; cf < 2; ++cf) {
        acc[0][cf] = __builtin_amdgcn_mfma_f32_16x16x32_bf16(a0, breg1[cf][ks], acc[0][cf], 0, 0, 0);
        acc[1][cf] = __builtin_amdgcn_mfma_f32_16x16x32_bf16(a1, breg1[cf][ks], acc[1][cf], 0, 0, 0);
      }
    }
#pragma unroll
    for (int rf = 0; rf < 2; ++rf)
#pragma unroll
      for (int cf = 0; cf < 2; ++cf) {
        int col = w * 32 + cf * 16 + row;
        float bias = be2[col];
#pragma unroll
        for (int r = 0; r < 4; ++r)
          zb[rf * 16 + (lane >> 4) * 4 + r][col] = acc[rf][cf][r] + bias;
      }
  }
  __syncthreads();

  if (tid < 128) {
    float s = 0.f, s2 = 0.f;
#pragma unroll 4
    for (int t = 0; t < 32; ++t) { float v = zb[t][tid]; s += v; s2 += v * v; }
    float mu = s * (1.f / 32.f);
    float var = (s2 - 32.f * mu * mu) * (1.f / 31.f);
    float rs = 1.f / sqrtf(fmaxf(var, 0.f) + EPS);
    float g = gamma[tid], be = beta[tid];
#pragma unroll 4
    for (int t = 0; t < 32; ++t) {
      unsigned short v = f2bf((zb[t][tid] - mu) * rs * g + be);
      int addr = (t * 512 + tid * 2) ^ ((t & 7) << 4);
      *reinterpret_cast<unsigned short*>(&zcs[addr]) = v;
    }
  } else if (tid < 160) {
    for (int t = 0; t < 32; ++t) {
      unsigned short v = (tid == 128) ? f2bf((float)t) : 0;
      int addr = (t * 512 + tid * 2) ^ ((t & 7) << 4);
      *reinterpret_cast<unsigned short*>(&zcs[addr]) = v;
    }
  }
  __syncthreads();

  {
    int n0 = nq * 256 + w * 64;
    short8 af[2][5];
#pragma unroll
    for (int rf = 0; rf < 2; ++rf)
#pragma unroll
      for (int ks = 0; ks < 5; ++ks) {
        int aoff = ((rf * 16 + row) * 512 + ks * 64 + kg * 2) ^ ((row & 7) << 4);
        af[rf][ks] = *reinterpret_cast<const short8*>(&zcs[aoff]);
      }
    short8 breg[4][5];
#pragma unroll
    for (int cf = 0; cf < 4; ++cf)
#pragma unroll
      for (int ks = 0; ks < 5; ++ks)
        breg[cf][ks] = *reinterpret_cast<const short8*>(
            Wg1T + (size_t)(n0 + cf * 16 + row) * 160 + ks * 32 + kg);
    f32x4 acc[2][4] = {{{0,0,0,0},{0,0,0,0},{0,0,0,0},{0,0,0,0}},
                       {{0,0,0,0},{0,0,0,0},{0,0,0,0},{0,0,0,0}}};
#pragma unroll
    for (int ks = 0; ks < 5; ++ks)
#pragma unroll
      for (int cf = 0; cf < 4; ++cf) {
        acc[0][cf] = __builtin_amdgcn_mfma_f32_16x16x32_bf16(af[0][ks], breg[cf][ks], acc[0][cf], 0, 0, 0);
        acc[1][cf] = __builtin_amdgcn_mfma_f32_16x16x32_bf16(af[1][ks], breg[cf][ks], acc[1][cf], 0, 0, 0);
      }
#pragma unroll
    for (int cf = 0; cf < 4; ++cf) {
      int n = n0 + cf * 16 + row;
      float bias = (n < 512) ? bg1[n] : 0.f;
#pragma unroll
      for (int rf = 0; rf < 2; ++rf)
#pragma unroll
        for (int r = 0; r < 4; ++r) {
          int t = rf * 16 + (lane >> 4) * 4 + r;
          g_all[((size_t)(b * 32 + t) << 10) + n] = f2bf(acc[rf][cf][r] + bias);
        }
    }
  }
}

// ---------------- k3: all_gp[hi][b] = sum over (ii in half, j) ---------------
// 1 block/CU (8 waves = full residency at ~256 combined regs). 2-deep A-ring,
// hstore split into quarters interleaved into the MFMA loop.
__global__ __launch_bounds__(512, 2) void k3(const unsigned short* __restrict__ g_all,
                                             const unsigned short* __restrict__ Wg2T,
                                             const float* __restrict__ bg2,
                                             float* __restrict__ all_gp) {
  __shared__ unsigned char ldsH[2][32768];   // [32][512] bf16 swizzled, dbuf
  int b = blockIdx.x >> 1, hi = blockIdx.x & 1;
  int ii0 = hi * 16;
  int tid = threadIdx.x, lane = tid & 63, w = tid >> 6;
  int row = lane & 15, kg = (lane >> 4) * 8;
  int cb = w * 32;
  int p = tid >> 4, kslot = tid & 15;

  // B-regs: Wg2T cols cb..cb+31, full K=512  (128 regs)
  short8 breg[2][16];
#pragma unroll
  for (int cf = 0; cf < 2; ++cf)
#pragma unroll
    for (int ks = 0; ks < 16; ++ks)
      breg[cf][ks] = *reinterpret_cast<const short8*>(
          Wg2T + (size_t)(cb + cf * 16 + row) * 512 + ks * 32 + kg);

  // gj cache packed bf16 (16 regs): gj[p][kslot*8 + q*128 + e]
  short8 gjr[4];
  {
    const unsigned short* gjp = g_all + ((size_t)(b * 32 + p) << 10) + 512 + kslot * 8;
#pragma unroll
    for (int q = 0; q < 4; ++q)
      gjr[q] = *reinterpret_cast<const short8*>(gjp + q * 128);
  }
  float biasv[2] = { bg2[cb + row], bg2[cb + 16 + row] };
  float accsum[2] = { 0.f, 0.f };

  short8 gv[4];   // gi loads in flight
  auto hload = [&](int ii) {
    const unsigned short* gi = g_all + ((size_t)(b * 32 + ii) << 10) + kslot * 8;
#pragma unroll
    for (int q = 0; q < 4; ++q)
      gv[q] = *reinterpret_cast<const short8*>(gi + q * 128);
  };
  auto hstore_q = [&](int buf, int q) {
    unsigned char* hb = &ldsH[buf][0] + p * 1024;
    float f0 = fmaxf(bf2f((unsigned short)gv[q][0]) + bf2f((unsigned short)gjr[q][0]), 0.f);
    float f1 = fmaxf(bf2f((unsigned short)gv[q][1]) + bf2f((unsigned short)gjr[q][1]), 0.f);
    float f2 = fmaxf(bf2f((unsigned short)gv[q][2]) + bf2f((unsigned short)gjr[q][2]), 0.f);
    float f3 = fmaxf(bf2f((unsigned short)gv[q][3]) + bf2f((unsigned short)gjr[q][3]), 0.f);
    float f4 = fmaxf(bf2f((unsigned short)gv[q][4]) + bf2f((unsigned short)gjr[q][4]), 0.f);
    float f5 = fmaxf(bf2f((unsigned short)gv[q][5]) + bf2f((unsigned short)gjr[q][5]), 0.f);
    float f6 = fmaxf(bf2f((unsigned short)gv[q][6]) + bf2f((unsigned short)gjr[q][6]), 0.f);
    float f7 = fmaxf(bf2f((unsigned short)gv[q][7]) + bf2f((unsigned short)gjr[q][7]), 0.f);
    uint4 pv;
    pv.x = pack_bf2(f0, f1); pv.y = pack_bf2(f2, f3);
    pv.z = pack_bf2(f4, f5); pv.w = pack_bf2(f6, f7);
    int addr = (kslot * 16 + q * 256) ^ ((p & 7) << 4);
    *reinterpret_cast<uint4*>(hb + addr) = pv;
  };

  hload(ii0);
#pragma unroll
  for (int q = 0; q < 4; ++q) hstore_q(0, q);
  __syncthreads();

  auto aread = [&](const unsigned char* hc, int r, int ks) {
    return *reinterpret_cast<const short8*>(
        hc + ((r * 1024 + ks * 64 + kg * 2) ^ ((r & 7) << 4)));
  };

  for (int it = 0; it < 16; ++it) {
    if (it < 15) hload(ii0 + it + 1);     // gi loads in flight across MFMA loop
    const unsigned char* hc = &ldsH[it & 1][0];
    int nbuf = (it + 1) & 1;
    bool more = (it < 15);
    f32x4 acc[2][2] = {{{0,0,0,0},{0,0,0,0}},{{0,0,0,0},{0,0,0,0}}};
    short8 ar[2][2];                      // 2-group-deep read ring
    ar[0][0] = aread(hc, row, 0);      ar[0][1] = aread(hc, 16 + row, 0);
    ar[1][0] = aread(hc, row, 1);      ar[1][1] = aread(hc, 16 + row, 1);
#pragma unroll
    for (int ks = 0; ks < 16; ++ks) {
      short8 c0v = ar[ks & 1][0], c1v = ar[ks & 1][1];
      if (ks < 14) {
        ar[ks & 1][0] = aread(hc, row, ks + 2);
        ar[ks & 1][1] = aread(hc, 16 + row, ks + 2);
      }
      __builtin_amdgcn_s_setprio(1);
      acc[0][0] = __builtin_amdgcn_mfma_f32_16x16x32_bf16(c0v, breg[0][ks], acc[0][0], 0, 0, 0);
      acc[0][1] = __builtin_amdgcn_mfma_f32_16x16x32_bf16(c0v, breg[1][ks], acc[0][1], 0, 0, 0);
      acc[1][0] = __builtin_amdgcn_mfma_f32_16x16x32_bf16(c1v, breg[0][ks], acc[1][0], 0, 0, 0);
      acc[1][1] = __builtin_amdgcn_mfma_f32_16x16x32_bf16(c1v, breg[1][ks], acc[1][1], 0, 0, 0);
      __builtin_amdgcn_s_setprio(0);
      if (more) {                         // spread next-tile H-gen through loop
        if (ks == 3)  hstore_q(nbuf, 0);
        if (ks == 6)  hstore_q(nbuf, 1);
        if (ks == 9)  hstore_q(nbuf, 2);
        if (ks == 12) hstore_q(nbuf, 3);
      }
    }
#pragma unroll
    for (int cf = 0; cf < 2; ++cf)
#pragma unroll
      for (int rf = 0; rf < 2; ++rf)
#pragma unroll
        for (int r = 0; r < 4; ++r)
          accsum[cf] += fmaxf(acc[rf][cf][r] + biasv[cf], 0.f);
    __syncthreads();
  }

#pragma unroll
  for (int cf = 0; cf < 2; ++cf) {
    accsum[cf] += __shfl_xor(accsum[cf], 16, 64);
    accsum[cf] += __shfl_xor(accsum[cf], 32, 64);
  }
  if ((lane >> 4) == 0) {
#pragma unroll
    for (int cf = 0; cf < 2; ++cf)
      all_gp[(size_t)(hi * 128 + b) * 256 + cb + cf * 16 + lane] = accsum[cf];
  }
}

// ---------------- k4: head (MFMA), sums 2 all_gp partials --------------------
__global__ __launch_bounds__(512) void k4(const float* __restrict__ all_gp,
                                          const unsigned short* __restrict__ WfT,
                                          const float* __restrict__ bfv,
                                          const float* __restrict__ Wy,
                                          const float* __restrict__ by,
                                          float* __restrict__ out) {
  __shared__ unsigned char As[8192];      // [16][256] bf16 swizzled
  __shared__ float fh[16][264];
  __shared__ float wys[1024];
  __shared__ float yvs[16][4];
  int tid = threadIdx.x, lane = tid & 63, w = tid >> 6;
  int row = lane & 15, kg = (lane >> 4) * 8;
  int m0 = blockIdx.x * 16;

  {
    int r = tid >> 5, c8 = (tid & 31) * 8;
    float s[8];
#pragma unroll
    for (int e = 0; e < 8; ++e) s[e] = 0.f;
#pragma unroll
    for (int q = 0; q < 2; ++q) {
      const float* p0 = all_gp + (size_t)(q * 128 + m0 + r) * 256 + c8;
      float4 a0 = *reinterpret_cast<const float4*>(p0);
      float4 a1 = *reinterpret_cast<const float4*>(p0 + 4);
      s[0] += a0.x; s[1] += a0.y; s[2] += a0.z; s[3] += a0.w;
      s[4] += a1.x; s[5] += a1.y; s[6] += a1.z; s[7] += a1.w;
    }
    uint4 pv;
    pv.x = pack_bf2(s[0], s[1]); pv.y = pack_bf2(s[2], s[3]);
    pv.z = pack_bf2(s[4], s[5]); pv.w = pack_bf2(s[6], s[7]);
    int addr = (r * 512 + c8 * 2) ^ ((r & 7) << 4);
    *reinterpret_cast<uint4*>(&As[addr]) = pv;
  }
  wys[tid] = Wy[tid];
  wys[tid + 512] = Wy[tid + 512];
  short8 breg[2][8];
#pragma unroll
  for (int cf = 0; cf < 2; ++cf)
#pragma unroll
    for (int ks = 0; ks < 8; ++ks)
      breg[cf][ks] = *reinterpret_cast<const short8*>(
          WfT + (size_t)(w * 32 + cf * 16 + row) * 256 + ks * 32 + kg);
  __syncthreads();

  f32x4 acc[2] = {{0,0,0,0},{0,0,0,0}};
#pragma unroll
  for (int ks = 0; ks < 8; ++ks) {
    int aoff = (row * 512 + ks * 64 + kg * 2) ^ ((row & 7) << 4);
    short8 af = *reinterpret_cast<const short8*>(&As[aoff]);
    acc[0] = __builtin_amdgcn_mfma_f32_16x16x32_bf16(af, breg[0][ks], acc[0], 0, 0, 0);
    acc[1] = __builtin_amdgcn_mfma_f32_16x16x32_bf16(af, breg[1][ks], acc[1], 0, 0, 0);
  }
#pragma unroll
  for (int cf = 0; cf < 2; ++cf) {
    int col = w * 32 + cf * 16 + row;
    float bias = bfv[col];
#pragma unroll
    for (int r = 0; r < 4; ++r)
      fh[(lane >> 4) * 4 + r][col] = fmaxf(acc[cf][r] + bias, 0.f);
  }
  __syncthreads();

  if (tid < 64) {
    int r = tid >> 2, o = tid & 3;
    float y = by[o];
#pragma unroll 4
    for (int k = 0; k < 256; ++k) y += fh[r][k] * wys[k * 4 + o];
    yvs[r][o] = y;
    out[(m0 + r) * 4 + o] = y;
  }
  __syncthreads();
  if (tid < 16) {
    int am = 0;
    float best = yvs[tid][0];
#pragma unroll
    for (int o = 1; o < 4; ++o)
      if (yvs[tid][o] > best) { best = yvs[tid][o]; am = o; }
    out[512 + m0 + tid] = (float)am;
  }
}

extern "C" void kernel_launch(void* const* d_in, const int* in_sizes, int n_in,
                              void* d_out, int out_size, void* d_ws, size_t ws_size,
                              hipStream_t stream) {
  const float* x     = (const float*)d_in[0];
  const float* We1   = (const float*)d_in[1];
  const float* be1   = (const float*)d_in[2];
  const float* We2   = (const float*)d_in[3];
  const float* be2   = (const float*)d_in[4];
  const float* gamma = (const float*)d_in[5];
  const float* beta  = (const float*)d_in[6];
  const float* Wg1   = (const float*)d_in[7];
  const float* bg1   = (const float*)d_in[8];
  const float* Wg2   = (const float*)d_in[9];
  const float* bg2   = (const float*)d_in[10];
  const float* Wf    = (const float*)d_in[11];
  const float* bff   = (const float*)d_in[12];
  const float* Wy    = (const float*)d_in[13];
  const float* by    = (const float*)d_in[14];

  char* ws = (char*)d_ws;
  unsigned short* h_bf  = (unsigned short*)(ws + 0);          // 2 MB
  unsigned short* g_all = (unsigned short*)(ws + 2097152);    // 8 MB
  unsigned short* We1T  = (unsigned short*)(ws + 10485760);   // 512 KB
  unsigned short* We2T  = (unsigned short*)(ws + 11010048);   // 64 KB
  unsigned short* Wg1T  = (unsigned short*)(ws + 11075584);   // 320 KB
  unsigned short* Wg2T  = (unsigned short*)(ws + 11403264);   // 256 KB
  float*          all_gp= (float*)(ws + 11665408);            // 256 KB [2][128][256]
  unsigned short* WfT   = (unsigned short*)(ws + 11927552);   // 128 KB
  float*          out   = (float*)d_out;

  k0_prep<<<2560, 256, 0, stream>>>(We1, We2, Wg1, Wg2, Wf, We1T, We2T, Wg1T, Wg2T, WfT);
  k1<<<256, 512, 0, stream>>>(x, We1T, be1, h_bf);
  k2<<<512, 256, 0, stream>>>(h_bf, We2T, be2, gamma, beta, Wg1T, bg1, g_all);
  k3<<<256, 512, 0, stream>>>(g_all, Wg2T, bg2, all_gp);
  k4<<<8, 512, 0, stream>>>(all_gp, WfT, bff, Wy, by, out);
}

// Round 8
// 95.994 us; speedup vs baseline: 1.0937x; 1.0937x over previous
//
#include <hip/hip_runtime.h>
#include <hip/hip_bf16.h>

#define EPS 1e-8f

typedef __attribute__((ext_vector_type(8))) short short8;
typedef __attribute__((ext_vector_type(4))) float f32x4;

__device__ __forceinline__ unsigned short f2bf(float f) {
  union { float f; unsigned u; } v; v.f = f;
  unsigned r = v.u + 0x7fffu + ((v.u >> 16) & 1u);
  return (unsigned short)(r >> 16);
}
__device__ __forceinline__ float bf2f(unsigned short b) {
  union { unsigned u; float f; } v; v.u = ((unsigned)b) << 16;
  return v.f;
}
__device__ __forceinline__ unsigned pack_bf2(float lo, float hi) {
  unsigned r;
  asm("v_cvt_pk_bf16_f32 %0, %1, %2" : "=v"(r) : "v"(lo), "v"(hi));
  return r;
}

// ---------------- k0: build bf16 transposed weights --------------------------
__global__ __launch_bounds__(256) void k0_prep(const float* __restrict__ We1,
                                               const float* __restrict__ We2,
                                               const float* __restrict__ Wg1,
                                               const float* __restrict__ Wg2,
                                               const float* __restrict__ Wf,
                                               unsigned short* __restrict__ We1T,
                                               unsigned short* __restrict__ We2T,
                                               unsigned short* __restrict__ Wg1T,
                                               unsigned short* __restrict__ Wg2T,
                                               unsigned short* __restrict__ WfT) {
  int idx = blockIdx.x * 256 + threadIdx.x;     // 655360 total
  if (idx < 262144) {
    int n = idx >> 10, k = idx & 1023;
    We1T[idx] = f2bf(We1[k * 256 + n]);
  } else if (idx < 294912) {
    int e = idx - 262144;
    int n = e >> 8, k = e & 255;
    We2T[e] = f2bf(We2[k * 128 + n]);
  } else if (idx < 458752) {
    int e = idx - 294912;
    int n = e / 160, c = e % 160;
    float v = 0.f;
    if (c < 129) v = (n < 512) ? Wg1[c * 512 + n] : Wg1[(129 + c) * 512 + (n - 512)];
    Wg1T[e] = f2bf(v);
  } else if (idx < 589824) {
    int e = idx - 458752;
    int n = e >> 9, k = e & 511;
    Wg2T[e] = f2bf(Wg2[k * 256 + n]);
  } else {
    int e = idx - 589824;
    int n = e >> 8, k = e & 255;
    WfT[e] = f2bf(Wf[k * 256 + n]);
  }
}

// ---------------- k1: h_bf = bf16(relu(x @ We1 + be1)) -----------------------
__global__ __launch_bounds__(512, 2) void k1(const float* __restrict__ x,
                                             const unsigned short* __restrict__ We1T,
                                             const float* __restrict__ be1,
                                             unsigned short* __restrict__ h_bf) {
  __shared__ unsigned char As[2][8192];   // [16][256] bf16, swizzled
  int tid = threadIdx.x, lane = tid & 63, w = tid >> 6;
  int m0 = blockIdx.x * 16;
  int srow = tid >> 5, skk = (tid & 31) * 8;
  int cb = w * 32;
  int row = lane & 15, kg = (lane >> 4) * 8;

  f32x4 acc[2] = {{0,0,0,0},{0,0,0,0}};

  auto stage = [&](int kc, int buf) {
    const float* src = x + (size_t)(m0 + srow) * 1024 + kc * 256 + skk;
    float4 a = *reinterpret_cast<const float4*>(src);
    float4 b = *reinterpret_cast<const float4*>(src + 4);
    uint4 pv;
    pv.x = pack_bf2(a.x, a.y); pv.y = pack_bf2(a.z, a.w);
    pv.z = pack_bf2(b.x, b.y); pv.w = pack_bf2(b.z, b.w);
    int addr = (srow * 512 + skk * 2) ^ ((srow & 7) << 4);
    *reinterpret_cast<uint4*>(&As[buf][addr]) = pv;
  };

  stage(0, 0);
  __syncthreads();
  for (int kc = 0; kc < 4; ++kc) {
    if (kc < 3) stage(kc + 1, (kc + 1) & 1);
    short8 breg[2][8];
#pragma unroll
    for (int cf = 0; cf < 2; ++cf)
#pragma unroll
      for (int ks = 0; ks < 8; ++ks)
        breg[cf][ks] = *reinterpret_cast<const short8*>(
            We1T + (size_t)(cb + cf * 16 + row) * 1024 + kc * 256 + ks * 32 + kg);
    const unsigned char* hc = &As[kc & 1][0];
#pragma unroll
    for (int ks = 0; ks < 8; ++ks) {
      int aoff = (row * 512 + ks * 64 + kg * 2) ^ ((row & 7) << 4);
      short8 af = *reinterpret_cast<const short8*>(hc + aoff);
      acc[0] = __builtin_amdgcn_mfma_f32_16x16x32_bf16(af, breg[0][ks], acc[0], 0, 0, 0);
      acc[1] = __builtin_amdgcn_mfma_f32_16x16x32_bf16(af, breg[1][ks], acc[1], 0, 0, 0);
    }
    __syncthreads();
  }
#pragma unroll
  for (int cf = 0; cf < 2; ++cf) {
    int col = cb + cf * 16 + row;
    float bias = be1[col];
#pragma unroll
    for (int r = 0; r < 4; ++r) {
      int orow = m0 + (lane >> 4) * 4 + r;
      h_bf[(size_t)orow * 256 + col] = f2bf(fmaxf(acc[cf][r] + bias, 0.f));
    }
  }
}

// ---------------- k2a: z = h@We2+be2 -> LN(T, ddof=1) -> zc [4096][160] bf16 --
__global__ __launch_bounds__(256) void k2a(const unsigned short* __restrict__ h_bf,
                                           const unsigned short* __restrict__ We2T,
                                           const float* __restrict__ be2,
                                           const float* __restrict__ gamma,
                                           const float* __restrict__ beta,
                                           unsigned short* __restrict__ zc) {
  __shared__ unsigned char zcs[16384];   // [32][256] bf16 swizzled (h tile)
  __shared__ float zb[32][132];
  int b = blockIdx.x, tid = threadIdx.x, lane = tid & 63, w = tid >> 6;
  int row = lane & 15, kg = (lane >> 4) * 8;

  {
    int srow = tid >> 3, skk = (tid & 7) * 32;
#pragma unroll
    for (int q = 0; q < 4; ++q) {
      short8 v = *reinterpret_cast<const short8*>(
          h_bf + (size_t)(b * 32 + srow) * 256 + skk + q * 8);
      int addr = (srow * 512 + (skk + q * 8) * 2) ^ ((srow & 7) << 4);
      *reinterpret_cast<short8*>(&zcs[addr]) = v;
    }
  }
  short8 breg1[2][8];
#pragma unroll
  for (int cf = 0; cf < 2; ++cf)
#pragma unroll
    for (int ks = 0; ks < 8; ++ks)
      breg1[cf][ks] = *reinterpret_cast<const short8*>(
          We2T + (size_t)(w * 32 + cf * 16 + row) * 256 + ks * 32 + kg);
  __syncthreads();

  {
    f32x4 acc[2][2] = {{{0,0,0,0},{0,0,0,0}},{{0,0,0,0},{0,0,0,0}}};
#pragma unroll
    for (int ks = 0; ks < 8; ++ks) {
      int a0off = (row * 512 + ks * 64 + kg * 2) ^ ((row & 7) << 4);
      int a1off = ((16 + row) * 512 + ks * 64 + kg * 2) ^ ((row & 7) << 4);
      short8 a0 = *reinterpret_cast<const short8*>(&zcs[a0off]);
      short8 a1 = *reinterpret_cast<const short8*>(&zcs[a1off]);
#pragma unroll
      for (int cf = 0; cf < 2; ++cf) {
        acc[0][cf] = __builtin_amdgcn_mfma_f32_16x16x32_bf16(a0, breg1[cf][ks], acc[0][cf], 0, 0, 0);
        acc[1][cf] = __builtin_amdgcn_mfma_f32_16x16x32_bf16(a1, breg1[cf][ks], acc[1][cf], 0, 0, 0);
      }
    }
#pragma unroll
    for (int rf = 0; rf < 2; ++rf)
#pragma unroll
      for (int cf = 0; cf < 2; ++cf) {
        int col = w * 32 + cf * 16 + row;
        float bias = be2[col];
#pragma unroll
        for (int r = 0; r < 4; ++r)
          zb[rf * 16 + (lane >> 4) * 4 + r][col] = acc[rf][cf][r] + bias;
      }
  }
  __syncthreads();

  if (tid < 128) {
    float s = 0.f, s2 = 0.f;
#pragma unroll 4
    for (int t = 0; t < 32; ++t) { float v = zb[t][tid]; s += v; s2 += v * v; }
    float mu = s * (1.f / 32.f);
    float var = (s2 - 32.f * mu * mu) * (1.f / 31.f);
    float rs = 1.f / sqrtf(fmaxf(var, 0.f) + EPS);
    float g = gamma[tid], be = beta[tid];
#pragma unroll 4
    for (int t = 0; t < 32; ++t)
      zc[(size_t)(b * 32 + t) * 160 + tid] = f2bf((zb[t][tid] - mu) * rs * g + be);
  } else if (tid < 160) {
    for (int t = 0; t < 32; ++t)
      zc[(size_t)(b * 32 + t) * 160 + tid] = (tid == 128) ? f2bf((float)t) : 0;
  }
}

// ---------------- k2b: g_all = zc @ Wg1T (+bg1 for n<512), M=4096 N=1024 K=160
__global__ __launch_bounds__(512, 4) void k2b(const unsigned short* __restrict__ zc,
                                              const unsigned short* __restrict__ Wg1T,
                                              const float* __restrict__ bg1,
                                              unsigned short* __restrict__ g_all) {
  __shared__ unsigned char As[16384];   // [32][256] bf16 swizzled
  int m0 = (blockIdx.x >> 2) * 32;
  int n0 = (blockIdx.x & 3) * 256;
  int tid = threadIdx.x, lane = tid & 63, w = tid >> 6;
  int row = lane & 15, kg = (lane >> 4) * 8;
  int c0 = n0 + w * 32;

  for (int ch = tid; ch < 640; ch += 512) {
    int r = ch / 20, c16 = ch % 20;
    short8 v = *reinterpret_cast<const short8*>(zc + (size_t)(m0 + r) * 160 + c16 * 8);
    int addr = (r * 512 + c16 * 16) ^ ((r & 7) << 4);
    *reinterpret_cast<short8*>(&As[addr]) = v;
  }
  short8 breg[2][5];
#pragma unroll
  for (int cf = 0; cf < 2; ++cf)
#pragma unroll
    for (int ks = 0; ks < 5; ++ks)
      breg[cf][ks] = *reinterpret_cast<const short8*>(
          Wg1T + (size_t)(c0 + cf * 16 + row) * 160 + ks * 32 + kg);
  __syncthreads();

  f32x4 acc[2][2] = {{{0,0,0,0},{0,0,0,0}},{{0,0,0,0},{0,0,0,0}}};
#pragma unroll
  for (int ks = 0; ks < 5; ++ks) {
    int a0off = (row * 512 + ks * 64 + kg * 2) ^ ((row & 7) << 4);
    int a1off = ((16 + row) * 512 + ks * 64 + kg * 2) ^ ((row & 7) << 4);
    short8 a0 = *reinterpret_cast<const short8*>(&As[a0off]);
    short8 a1 = *reinterpret_cast<const short8*>(&As[a1off]);
#pragma unroll
    for (int cf = 0; cf < 2; ++cf) {
      acc[0][cf] = __builtin_amdgcn_mfma_f32_16x16x32_bf16(a0, breg[cf][ks], acc[0][cf], 0, 0, 0);
      acc[1][cf] = __builtin_amdgcn_mfma_f32_16x16x32_bf16(a1, breg[cf][ks], acc[1][cf], 0, 0, 0);
    }
  }
#pragma unroll
  for (int cf = 0; cf < 2; ++cf) {
    int n = c0 + cf * 16 + row;
    float bias = (n < 512) ? bg1[n] : 0.f;
#pragma unroll
    for (int rf = 0; rf < 2; ++rf)
#pragma unroll
      for (int r = 0; r < 4; ++r) {
        int mrow = m0 + rf * 16 + (lane >> 4) * 4 + r;
        g_all[((size_t)mrow << 10) + n] = f2bf(acc[rf][cf][r] + bias);
      }
  }
}

// ---------------- k3: all_gp[hi][b] = sum over (ii in half, j) ---------------
// 2 sub-tiles (2 ii) per barrier, processed sequentially (acc reused -> no
// extra liveness). LDS 2 x 2 x 32KB = 128KB, 1 block/CU, 8 iters.
__global__ __launch_bounds__(512, 2) void k3(const unsigned short* __restrict__ g_all,
                                             const unsigned short* __restrict__ Wg2T,
                                             const float* __restrict__ bg2,
                                             float* __restrict__ all_gp) {
  __shared__ unsigned char ldsH[2][2][32768];   // [buf][sub][32][512] bf16 swizzled
  int b = blockIdx.x >> 1, hi = blockIdx.x & 1;
  int ii0 = hi * 16;
  int tid = threadIdx.x, lane = tid & 63, w = tid >> 6;
  int row = lane & 15, kg = (lane >> 4) * 8;
  int cb = w * 32;
  int p = tid >> 4, kslot = tid & 15;

  // B-regs: Wg2T cols cb..cb+31, full K=512  (128 regs)
  short8 breg[2][16];
#pragma unroll
  for (int cf = 0; cf < 2; ++cf)
#pragma unroll
    for (int ks = 0; ks < 16; ++ks)
      breg[cf][ks] = *reinterpret_cast<const short8*>(
          Wg2T + (size_t)(cb + cf * 16 + row) * 512 + ks * 32 + kg);

  // gj cache packed bf16 (16 regs)
  short8 gjr[4];
  {
    const unsigned short* gjp = g_all + ((size_t)(b * 32 + p) << 10) + 512 + kslot * 8;
#pragma unroll
    for (int q = 0; q < 4; ++q)
      gjr[q] = *reinterpret_cast<const short8*>(gjp + q * 128);
  }
  float biasv[2] = { bg2[cb + row], bg2[cb + 16 + row] };
  float accsum[2] = { 0.f, 0.f };

  short8 gv[4];   // gi loads in flight (consumed by next hstore)
  auto hload = [&](int ii) {
    const unsigned short* gi = g_all + ((size_t)(b * 32 + ii) << 10) + kslot * 8;
#pragma unroll
    for (int q = 0; q < 4; ++q)
      gv[q] = *reinterpret_cast<const short8*>(gi + q * 128);
  };
  auto hstore = [&](int buf, int sub) {
    unsigned char* hb = &ldsH[buf][sub][0] + p * 1024;
#pragma unroll
    for (int q = 0; q < 4; ++q) {
      float f0 = fmaxf(bf2f((unsigned short)gv[q][0]) + bf2f((unsigned short)gjr[q][0]), 0.f);
      float f1 = fmaxf(bf2f((unsigned short)gv[q][1]) + bf2f((unsigned short)gjr[q][1]), 0.f);
      float f2 = fmaxf(bf2f((unsigned short)gv[q][2]) + bf2f((unsigned short)gjr[q][2]), 0.f);
      float f3 = fmaxf(bf2f((unsigned short)gv[q][3]) + bf2f((unsigned short)gjr[q][3]), 0.f);
      float f4 = fmaxf(bf2f((unsigned short)gv[q][4]) + bf2f((unsigned short)gjr[q][4]), 0.f);
      float f5 = fmaxf(bf2f((unsigned short)gv[q][5]) + bf2f((unsigned short)gjr[q][5]), 0.f);
      float f6 = fmaxf(bf2f((unsigned short)gv[q][6]) + bf2f((unsigned short)gjr[q][6]), 0.f);
      float f7 = fmaxf(bf2f((unsigned short)gv[q][7]) + bf2f((unsigned short)gjr[q][7]), 0.f);
      uint4 pv;
      pv.x = pack_bf2(f0, f1); pv.y = pack_bf2(f2, f3);
      pv.z = pack_bf2(f4, f5); pv.w = pack_bf2(f6, f7);
      int addr = (kslot * 16 + q * 256) ^ ((p & 7) << 4);
      *reinterpret_cast<uint4*>(hb + addr) = pv;
    }
  };
  auto aread = [&](const unsigned char* hc, int r, int ks) {
    return *reinterpret_cast<const short8*>(
        hc + ((r * 1024 + ks * 64 + kg * 2) ^ ((r & 7) << 4)));
  };
  auto subtile = [&](int buf, int sub) {
    const unsigned char* hc = &ldsH[buf][sub][0];
    f32x4 acc[2][2] = {{{0,0,0,0},{0,0,0,0}},{{0,0,0,0},{0,0,0,0}}};
    short8 a0 = aread(hc, row, 0);
    short8 a1 = aread(hc, 16 + row, 0);
#pragma unroll
    for (int ks = 0; ks < 16; ++ks) {
      short8 c0v = a0, c1v = a1;
      if (ks < 15) {
        a0 = aread(hc, row, ks + 1);
        a1 = aread(hc, 16 + row, ks + 1);
      }
      __builtin_amdgcn_s_setprio(1);
      acc[0][0] = __builtin_amdgcn_mfma_f32_16x16x32_bf16(c0v, breg[0][ks], acc[0][0], 0, 0, 0);
      acc[0][1] = __builtin_amdgcn_mfma_f32_16x16x32_bf16(c0v, breg[1][ks], acc[0][1], 0, 0, 0);
      acc[1][0] = __builtin_amdgcn_mfma_f32_16x16x32_bf16(c1v, breg[0][ks], acc[1][0], 0, 0, 0);
      acc[1][1] = __builtin_amdgcn_mfma_f32_16x16x32_bf16(c1v, breg[1][ks], acc[1][1], 0, 0, 0);
      __builtin_amdgcn_s_setprio(0);
    }
#pragma unroll
    for (int cf = 0; cf < 2; ++cf)
#pragma unroll
      for (int rf = 0; rf < 2; ++rf)
#pragma unroll
        for (int r = 0; r < 4; ++r)
          accsum[cf] += fmaxf(acc[rf][cf][r] + biasv[cf], 0.f);
  };

  // prologue: fill buf0 with ii0, ii0+1
  hload(ii0);     hstore(0, 0);
  hload(ii0 + 1); hstore(0, 1);
  __syncthreads();

  for (int it = 0; it < 8; ++it) {
    int cur = it & 1, nxt = cur ^ 1;
    bool more = (it < 7);
    if (more) hload(ii0 + 2 * it + 2);   // in flight across sub-0 MFMAs
    subtile(cur, 0);
    if (more) {
      hstore(nxt, 0);
      hload(ii0 + 2 * it + 3);           // in flight across sub-1 MFMAs
    }
    subtile(cur, 1);
    if (more) hstore(nxt, 1);
    __syncthreads();
  }

#pragma unroll
  for (int cf = 0; cf < 2; ++cf) {
    accsum[cf] += __shfl_xor(accsum[cf], 16, 64);
    accsum[cf] += __shfl_xor(accsum[cf], 32, 64);
  }
  if ((lane >> 4) == 0) {
#pragma unroll
    for (int cf = 0; cf < 2; ++cf)
      all_gp[(size_t)(hi * 128 + b) * 256 + cb + cf * 16 + lane] = accsum[cf];
  }
}

// ---------------- k4: head (MFMA), sums 2 all_gp partials --------------------
__global__ __launch_bounds__(512) void k4(const float* __restrict__ all_gp,
                                          const unsigned short* __restrict__ WfT,
                                          const float* __restrict__ bfv,
                                          const float* __restrict__ Wy,
                                          const float* __restrict__ by,
                                          float* __restrict__ out) {
  __shared__ unsigned char As[8192];      // [16][256] bf16 swizzled
  __shared__ float fh[16][264];
  __shared__ float wys[1024];
  __shared__ float yvs[16][4];
  int tid = threadIdx.x, lane = tid & 63, w = tid >> 6;
  int row = lane & 15, kg = (lane >> 4) * 8;
  int m0 = blockIdx.x * 16;

  {
    int r = tid >> 5, c8 = (tid & 31) * 8;
    float s[8];
#pragma unroll
    for (int e = 0; e < 8; ++e) s[e] = 0.f;
#pragma unroll
    for (int q = 0; q < 2; ++q) {
      const float* p0 = all_gp + (size_t)(q * 128 + m0 + r) * 256 + c8;
      float4 a0 = *reinterpret_cast<const float4*>(p0);
      float4 a1 = *reinterpret_cast<const float4*>(p0 + 4);
      s[0] += a0.x; s[1] += a0.y; s[2] += a0.z; s[3] += a0.w;
      s[4] += a1.x; s[5] += a1.y; s[6] += a1.z; s[7] += a1.w;
    }
    uint4 pv;
    pv.x = pack_bf2(s[0], s[1]); pv.y = pack_bf2(s[2], s[3]);
    pv.z = pack_bf2(s[4], s[5]); pv.w = pack_bf2(s[6], s[7]);
    int addr = (r * 512 + c8 * 2) ^ ((r & 7) << 4);
    *reinterpret_cast<uint4*>(&As[addr]) = pv;
  }
  wys[tid] = Wy[tid];
  wys[tid + 512] = Wy[tid + 512];
  short8 breg[2][8];
#pragma unroll
  for (int cf = 0; cf < 2; ++cf)
#pragma unroll
    for (int ks = 0; ks < 8; ++ks)
      breg[cf][ks] = *reinterpret_cast<const short8*>(
          WfT + (size_t)(w * 32 + cf * 16 + row) * 256 + ks * 32 + kg);
  __syncthreads();

  f32x4 acc[2] = {{0,0,0,0},{0,0,0,0}};
#pragma unroll
  for (int ks = 0; ks < 8; ++ks) {
    int aoff = (row * 512 + ks * 64 + kg * 2) ^ ((row & 7) << 4);
    short8 af = *reinterpret_cast<const short8*>(&As[aoff]);
    acc[0] = __builtin_amdgcn_mfma_f32_16x16x32_bf16(af, breg[0][ks], acc[0], 0, 0, 0);
    acc[1] = __builtin_amdgcn_mfma_f32_16x16x32_bf16(af, breg[1][ks], acc[1], 0, 0, 0);
  }
#pragma unroll
  for (int cf = 0; cf < 2; ++cf) {
    int col = w * 32 + cf * 16 + row;
    float bias = bfv[col];
#pragma unroll
    for (int r = 0; r < 4; ++r)
      fh[(lane >> 4) * 4 + r][col] = fmaxf(acc[cf][r] + bias, 0.f);
  }
  __syncthreads();

  if (tid < 64) {
    int r = tid >> 2, o = tid & 3;
    float y = by[o];
#pragma unroll 4
    for (int k = 0; k < 256; ++k) y += fh[r][k] * wys[k * 4 + o];
    yvs[r][o] = y;
    out[(m0 + r) * 4 + o] = y;
  }
  __syncthreads();
  if (tid < 16) {
    int am = 0;
    float best = yvs[tid][0];
#pragma unroll
    for (int o = 1; o < 4; ++o)
      if (yvs[tid][o] > best) { best = yvs[tid][o]; am = o; }
    out[512 + m0 + tid] = (float)am;
  }
}

extern "C" void kernel_launch(void* const* d_in, const int* in_sizes, int n_in,
                              void* d_out, int out_size, void* d_ws, size_t ws_size,
                              hipStream_t stream) {
  const float* x     = (const float*)d_in[0];
  const float* We1   = (const float*)d_in[1];
  const float* be1   = (const float*)d_in[2];
  const float* We2   = (const float*)d_in[3];
  const float* be2   = (const float*)d_in[4];
  const float* gamma = (const float*)d_in[5];
  const float* beta  = (const float*)d_in[6];
  const float* Wg1   = (const float*)d_in[7];
  const float* bg1   = (const float*)d_in[8];
  const float* Wg2   = (const float*)d_in[9];
  const float* bg2   = (const float*)d_in[10];
  const float* Wf    = (const float*)d_in[11];
  const float* bff   = (const float*)d_in[12];
  const float* Wy    = (const float*)d_in[13];
  const float* by    = (const float*)d_in[14];

  char* ws = (char*)d_ws;
  unsigned short* h_bf  = (unsigned short*)(ws + 0);          // 2 MB
  unsigned short* g_all = (unsigned short*)(ws + 2097152);    // 8 MB
  unsigned short* We1T  = (unsigned short*)(ws + 10485760);   // 512 KB
  unsigned short* We2T  = (unsigned short*)(ws + 11010048);   // 64 KB
  unsigned short* Wg1T  = (unsigned short*)(ws + 11075584);   // 320 KB
  unsigned short* Wg2T  = (unsigned short*)(ws + 11403264);   // 256 KB
  float*          all_gp= (float*)(ws + 11665408);            // 256 KB [2][128][256]
  unsigned short* WfT   = (unsigned short*)(ws + 11927552);   // 128 KB
  unsigned short* zc    = (unsigned short*)(ws + 12058624);   // 1.31 MB
  float*          out   = (float*)d_out;

  k0_prep<<<2560, 256, 0, stream>>>(We1, We2, Wg1, Wg2, Wf, We1T, We2T, Wg1T, Wg2T, WfT);
  k1<<<256, 512, 0, stream>>>(x, We1T, be1, h_bf);
  k2a<<<128, 256, 0, stream>>>(h_bf, We2T, be2, gamma, beta, zc);
  k2b<<<512, 512, 0, stream>>>(zc, Wg1T, bg1, g_all);
  k3<<<256, 512, 0, stream>>>(g_all, Wg2T, bg2, all_gp);
  k4<<<8, 512, 0, stream>>>(all_gp, WfT, bff, Wy, by, out);
}